// Round 1
// baseline (698.560 us; speedup 1.0000x reference)
//
#include <hip/hip_runtime.h>
#include <math.h>

// EncoderBlock: pre-LN attention + FFN, bf16 MFMA compute, fp32 residual spine.
// B=4 T=2048 D=1024 H=16 dk=64 DFF=4096

#define D_MODEL 1024
#define D_FF    4096
#define NH      16
#define BATCH   4
#define SEQ     2048
#define DK      64
#define MTOK    (BATCH*SEQ)   // 8192
#define NBH     (BATCH*NH)    // 64

typedef __bf16 bf16;
typedef bf16  bf16x4 __attribute__((ext_vector_type(4)));
typedef bf16  bf16x8 __attribute__((ext_vector_type(8)));
typedef float f32x4  __attribute__((ext_vector_type(4)));

__device__ __forceinline__ void gload_lds16(const bf16* g, bf16* l) {
  __builtin_amdgcn_global_load_lds(
      (__attribute__((address_space(1))) void*)g,
      (__attribute__((address_space(3))) void*)l, 16, 0, 0);
}

// ---------------- fp32 -> bf16 cast (weights) ----------------
__global__ __launch_bounds__(256) void cast_w(const float* __restrict__ s,
                                              bf16* __restrict__ d, int n) {
  int i = (blockIdx.x * 256 + threadIdx.x) * 4;
  if (i >= n) return;
  float4 v = *(const float4*)(s + i);
  bf16x4 o;
  o[0] = (bf16)v.x; o[1] = (bf16)v.y; o[2] = (bf16)v.z; o[3] = (bf16)v.w;
  *(bf16x4*)(d + i) = o;
}

// ---------------- LayerNorm (fp32 in, bf16 out) ----------------
__global__ __launch_bounds__(256) void ln_kernel(const float* __restrict__ x,
                                                 const float* __restrict__ g,
                                                 const float* __restrict__ b,
                                                 bf16* __restrict__ out) {
  int row = blockIdx.x;
  int tid = threadIdx.x;
  const float* xr = x + (size_t)row * D_MODEL;
  float4 v = *(const float4*)(xr + tid * 4);
  float s  = v.x + v.y + v.z + v.w;
  float sq = v.x*v.x + v.y*v.y + v.z*v.z + v.w*v.w;
  #pragma unroll
  for (int off = 1; off < 64; off <<= 1) {
    s  += __shfl_xor(s,  off, 64);
    sq += __shfl_xor(sq, off, 64);
  }
  __shared__ float ls[4], lq[4];
  int wid = tid >> 6, lane = tid & 63;
  if (lane == 0) { ls[wid] = s; lq[wid] = sq; }
  __syncthreads();
  s  = ls[0] + ls[1] + ls[2] + ls[3];
  sq = lq[0] + lq[1] + lq[2] + lq[3];
  float mu   = s * (1.0f / D_MODEL);
  float var  = sq * (1.0f / D_MODEL) - mu * mu;
  float rstd = rsqrtf(var + 1e-5f);
  float4 gv = *(const float4*)(g + tid * 4);
  float4 bv = *(const float4*)(b + tid * 4);
  bf16x4 o;
  o[0] = (bf16)((v.x - mu) * rstd * gv.x + bv.x);
  o[1] = (bf16)((v.y - mu) * rstd * gv.y + bv.y);
  o[2] = (bf16)((v.z - mu) * rstd * gv.z + bv.z);
  o[3] = (bf16)((v.w - mu) * rstd * gv.w + bv.w);
  *(bf16x4*)(out + (size_t)row * D_MODEL + tid * 4) = o;
}

// ---------------- GEMM: C[M,N] = A[M,K] @ W[N,K]^T (+bias, epilogue) --------
// 128x128 tile, BK=64, 4 waves (2x2), 16x16x32 bf16 MFMA (m97 structure).
enum { EP_QKV = 0, EP_RESID = 1, EP_GELU = 2 };

template <int EP>
__global__ __launch_bounds__(256) void gemm_bt(
    const bf16* __restrict__ A, const bf16* __restrict__ W,
    const float* __restrict__ bias,
    const float* __restrict__ resid,   // EP_RESID: fp32 residual input
    float* __restrict__ out_f32,       // EP_RESID dst
    bf16* __restrict__ out_bf,         // EP_QKV: qkv base [3][BH][T][DK]; EP_GELU: [M,N]
    int M, int N, int K) {
  __shared__ bf16 lA[128 * 64];
  __shared__ bf16 lB[128 * 64];
  int tiles_n = N >> 7;
  int bm = blockIdx.x / tiles_n, bn = blockIdx.x % tiles_n;
  int m0 = bm << 7, n0 = bn << 7;
  int tid = threadIdx.x, wid = tid >> 6, lane = tid & 63;
  int wm = wid >> 1, wn = wid & 1;
  int l15 = lane & 15, l4 = lane >> 4;

  f32x4 acc[4][4];
  #pragma unroll
  for (int i = 0; i < 4; i++)
    #pragma unroll
    for (int n = 0; n < 4; n++)
      #pragma unroll
      for (int e = 0; e < 4; e++) acc[i][n][e] = 0.f;

  int rA = tid >> 3;           // 0..31
  int c8 = (tid & 7) << 3;     // 0..56
  const bf16* gA = A + (size_t)(m0 + rA) * K + c8;
  const bf16* gW = W + (size_t)(n0 + rA) * K + c8;
  bf16* lAbase = lA + (wid << 9);
  bf16* lBbase = lB + (wid << 9);

  for (int kt = 0; kt < K; kt += 64) {
    __syncthreads();
    #pragma unroll
    for (int it = 0; it < 4; ++it) {
      gload_lds16(gA + (size_t)(it * 32) * K + kt, lAbase + it * 2048);
      gload_lds16(gW + (size_t)(it * 32) * K + kt, lBbase + it * 2048);
    }
    __syncthreads();
    #pragma unroll
    for (int kk = 0; kk < 2; ++kk) {
      bf16x8 af[4], bfr[4];
      #pragma unroll
      for (int i = 0; i < 4; i++) {
        af[i]  = *(const bf16x8*)(lA + (wm * 64 + i * 16 + l15) * 64 + kk * 32 + (l4 << 3));
        bfr[i] = *(const bf16x8*)(lB + (wn * 64 + i * 16 + l15) * 64 + kk * 32 + (l4 << 3));
      }
      #pragma unroll
      for (int i = 0; i < 4; i++)
        #pragma unroll
        for (int n = 0; n < 4; n++)
          acc[i][n] = __builtin_amdgcn_mfma_f32_16x16x32_bf16(af[i], bfr[n], acc[i][n], 0, 0, 0);
    }
  }

  #pragma unroll
  for (int i = 0; i < 4; i++)
    #pragma unroll
    for (int n = 0; n < 4; n++)
      #pragma unroll
      for (int j = 0; j < 4; j++) {
        int gm = m0 + wm * 64 + i * 16 + (l4 << 2) + j;
        int gn = n0 + wn * 64 + n * 16 + l15;
        float cv = acc[i][n][j] + bias[gn];
        if (EP == EP_QKV) {
          int which = gn >> 10;          // 0=q 1=k 2=v
          int nn = gn & 1023;
          int head = nn >> 6, d = nn & 63;
          int bb = gm >> 11, t = gm & 2047;
          size_t idx = (size_t)which * (NBH * SEQ * DK) +
                       ((size_t)(bb * NH + head) * SEQ + t) * DK + d;
          out_bf[idx] = (bf16)cv;
        } else if (EP == EP_RESID) {
          size_t idx = (size_t)gm * N + gn;
          out_f32[idx] = resid[idx] + cv;
        } else {  // EP_GELU (exact erf)
          float ge = 0.5f * cv * (1.0f + erff(cv * 0.70710678118654752f));
          out_bf[(size_t)gm * N + gn] = (bf16)ge;
        }
      }
}

// ---------------- Flash attention ----------------
// grid: (T/64) * BH blocks, 256 thr. Wave w owns 16 q-rows. KVBLK=64.
// q,k,v: [BH][T][DK] bf16.  o: [B][T][D_MODEL] bf16 (head-interleaved).
__global__ __launch_bounds__(256) void attn_kernel(
    const bf16* __restrict__ q, const bf16* __restrict__ k,
    const bf16* __restrict__ v, bf16* __restrict__ o) {
  __shared__ bf16 kt_lds[64 * 64];      // K tile [kv][d]
  __shared__ bf16 vt_lds[64 * 64];      // V^T tile [d][kv]
  __shared__ bf16 p_lds[4][16 * 64];    // per-wave P [qrow][kv]
  int bid = blockIdx.x;
  int bh = bid >> 5;                     // T/64 = 32 q-tiles
  int qt = bid & 31;
  int t0 = qt << 6;
  int tid = threadIdx.x, wid = tid >> 6, lane = tid & 63;
  int l15 = lane & 15, l4 = lane >> 4;

  // Q fragments (A-operand): rows t0 + wid*16 + l15
  const bf16* qbase = q + ((size_t)bh * SEQ + t0 + wid * 16 + l15) * DK;
  bf16x8 qf[2];
  qf[0] = *(const bf16x8*)(qbase + (l4 << 3));
  qf[1] = *(const bf16x8*)(qbase + 32 + (l4 << 3));

  float m_run[4], l_run[4];
  f32x4 acc_o[4];
  #pragma unroll
  for (int j = 0; j < 4; j++) { m_run[j] = -1e30f; l_run[j] = 0.f; }
  #pragma unroll
  for (int n = 0; n < 4; n++)
    #pragma unroll
    for (int e = 0; e < 4; e++) acc_o[n][e] = 0.f;

  int rK = tid >> 3, cK = (tid & 7) << 3;
  const bf16* gK = k + ((size_t)bh * SEQ + rK) * DK + cK;
  bf16* lKbase = kt_lds + (wid << 9);
  int rV = tid >> 2, cV = (tid & 3) << 4;
  const bf16* gV = v + ((size_t)bh * SEQ + rV) * DK + cV;

  for (int kv0 = 0; kv0 < SEQ; kv0 += 64) {
    __syncthreads();
    #pragma unroll
    for (int it = 0; it < 2; ++it)
      gload_lds16(gK + (size_t)(kv0 + it * 32) * DK, lKbase + it * 2048);
    bf16x8 v0 = *(const bf16x8*)(gV + (size_t)kv0 * DK);
    bf16x8 v1 = *(const bf16x8*)(gV + (size_t)kv0 * DK + 8);
    #pragma unroll
    for (int jj = 0; jj < 8; jj++) {
      vt_lds[(cV + jj) * 64 + rV]     = v0[jj];
      vt_lds[(cV + 8 + jj) * 64 + rV] = v1[jj];
    }
    __syncthreads();

    // S = Q K^T  (scaled later in fp32)
    f32x4 accs[4];
    #pragma unroll
    for (int n = 0; n < 4; n++) {
      #pragma unroll
      for (int e = 0; e < 4; e++) accs[n][e] = 0.f;
      #pragma unroll
      for (int kk = 0; kk < 2; kk++) {
        bf16x8 kf = *(const bf16x8*)(kt_lds + (n * 16 + l15) * 64 + kk * 32 + (l4 << 3));
        accs[n] = __builtin_amdgcn_mfma_f32_16x16x32_bf16(qf[kk], kf, accs[n], 0, 0, 0);
      }
    }
    // online softmax per owned row j (row = l4*4+j), reduce across 16 lanes
    float p[4][4];
    #pragma unroll
    for (int j = 0; j < 4; j++) {
      float mx = -1e30f;
      #pragma unroll
      for (int n = 0; n < 4; n++) { accs[n][j] *= 0.125f; mx = fmaxf(mx, accs[n][j]); }
      #pragma unroll
      for (int off = 1; off < 16; off <<= 1) mx = fmaxf(mx, __shfl_xor(mx, off, 64));
      float mn = fmaxf(m_run[j], mx);
      float sc = __expf(m_run[j] - mn);
      m_run[j] = mn;
      float rs = 0.f;
      #pragma unroll
      for (int n = 0; n < 4; n++) { float pv = __expf(accs[n][j] - mn); p[n][j] = pv; rs += pv; }
      #pragma unroll
      for (int off = 1; off < 16; off <<= 1) rs += __shfl_xor(rs, off, 64);
      l_run[j] = l_run[j] * sc + rs;
      #pragma unroll
      for (int n = 0; n < 4; n++) acc_o[n][j] *= sc;
    }
    // P: D-layout -> LDS -> A-layout
    #pragma unroll
    for (int j = 0; j < 4; j++)
      #pragma unroll
      for (int n = 0; n < 4; n++)
        p_lds[wid][(l4 * 4 + j) * 64 + n * 16 + l15] = (bf16)p[n][j];
    #pragma unroll
    for (int kk = 0; kk < 2; kk++) {
      bf16x8 pa = *(const bf16x8*)(&p_lds[wid][l15 * 64 + kk * 32 + (l4 << 3)]);
      #pragma unroll
      for (int nd = 0; nd < 4; nd++) {
        bf16x8 vf = *(const bf16x8*)(vt_lds + (nd * 16 + l15) * 64 + kk * 32 + (l4 << 3));
        acc_o[nd] = __builtin_amdgcn_mfma_f32_16x16x32_bf16(pa, vf, acc_o[nd], 0, 0, 0);
      }
    }
  }
  int bb = bh >> 4, hh = bh & 15;
  #pragma unroll
  for (int nd = 0; nd < 4; nd++)
    #pragma unroll
    for (int j = 0; j < 4; j++) {
      int row = t0 + wid * 16 + l4 * 4 + j;
      int d = nd * 16 + l15;
      float ov = acc_o[nd][j] / l_run[j];
      o[((size_t)bb * SEQ + row) * D_MODEL + hh * DK + d] = (bf16)ov;
    }
}

// ---------------- launch ----------------
extern "C" void kernel_launch(void* const* d_in, const int* in_sizes, int n_in,
                              void* d_out, int out_size, void* d_ws, size_t ws_size,
                              hipStream_t stream) {
  const float* x    = (const float*)d_in[0];
  const float* ln1g = (const float*)d_in[1];
  const float* ln1b = (const float*)d_in[2];
  const float* wq   = (const float*)d_in[3];
  const float* bq   = (const float*)d_in[4];
  const float* wk   = (const float*)d_in[5];
  const float* bk   = (const float*)d_in[6];
  const float* wv   = (const float*)d_in[7];
  const float* bv   = (const float*)d_in[8];
  const float* wo   = (const float*)d_in[9];
  const float* bo   = (const float*)d_in[10];
  const float* ln2g = (const float*)d_in[11];
  const float* ln2b = (const float*)d_in[12];
  const float* w1   = (const float*)d_in[13];
  const float* b1   = (const float*)d_in[14];
  const float* w2   = (const float*)d_in[15];
  const float* b2   = (const float*)d_in[16];
  float* out = (float*)d_out;

  char* ws = (char*)d_ws;
  bf16* wqkv_b = (bf16*)(ws);                          // [3072,1024]  6MB
  bf16* wo_b   = (bf16*)(ws + ((size_t)6  << 20));     // 2MB
  bf16* w1_b   = (bf16*)(ws + ((size_t)8  << 20));     // 8MB
  bf16* w2_b   = (bf16*)(ws + ((size_t)16 << 20));     // 8MB
  bf16* h_b    = (bf16*)(ws + ((size_t)24 << 20));     // 16MB (h, later h2)
  bf16* qkv_b  = (bf16*)(ws + ((size_t)40 << 20));     // 48MB q|k|v
  bf16* o_b    = (bf16*)(ws + ((size_t)88 << 20));     // 16MB
  bf16* ffn1_b = (bf16*)(ws + ((size_t)40 << 20));     // 64MB (over dead q,k,v,o)
  float* bqkv  = (float*)(ws + ((size_t)104 << 20));   // 12KB

  cast_w<<<1024, 256, 0, stream>>>(wq, wqkv_b, 1 << 20);
  cast_w<<<1024, 256, 0, stream>>>(wk, wqkv_b + (1 << 20), 1 << 20);
  cast_w<<<1024, 256, 0, stream>>>(wv, wqkv_b + (2 << 20), 1 << 20);
  cast_w<<<1024, 256, 0, stream>>>(wo, wo_b, 1 << 20);
  cast_w<<<4096, 256, 0, stream>>>(w1, w1_b, 1 << 22);
  cast_w<<<4096, 256, 0, stream>>>(w2, w2_b, 1 << 22);
  hipMemcpyAsync(bqkv,        bq, 4096, hipMemcpyDeviceToDevice, stream);
  hipMemcpyAsync(bqkv + 1024, bk, 4096, hipMemcpyDeviceToDevice, stream);
  hipMemcpyAsync(bqkv + 2048, bv, 4096, hipMemcpyDeviceToDevice, stream);

  ln_kernel<<<MTOK, 256, 0, stream>>>(x, ln1g, ln1b, h_b);
  gemm_bt<EP_QKV><<<64 * 24, 256, 0, stream>>>(h_b, wqkv_b, bqkv, nullptr, nullptr,
                                               qkv_b, MTOK, 3072, 1024);
  attn_kernel<<<NBH * 32, 256, 0, stream>>>(qkv_b, qkv_b + (size_t)NBH * SEQ * DK,
                                            qkv_b + (size_t)2 * NBH * SEQ * DK, o_b);
  gemm_bt<EP_RESID><<<64 * 8, 256, 0, stream>>>(o_b, wo_b, bo, x, out, nullptr,
                                                MTOK, 1024, 1024);
  ln_kernel<<<MTOK, 256, 0, stream>>>(out, ln2g, ln2b, h_b);
  gemm_bt<EP_GELU><<<64 * 32, 256, 0, stream>>>(h_b, w1_b, b1, nullptr, nullptr,
                                                ffn1_b, MTOK, 4096, 1024);
  gemm_bt<EP_RESID><<<64 * 8, 256, 0, stream>>>(ffn1_b, w2_b, b2, out, out, nullptr,
                                                MTOK, 1024, 4096);
}

// Round 2
// 620.544 us; speedup vs baseline: 1.1257x; 1.1257x over previous
//
#include <hip/hip_runtime.h>
#include <math.h>

// EncoderBlock: pre-LN attention + FFN, bf16 MFMA compute, fp32 residual spine.
// B=4 T=2048 D=1024 H=16 dk=64 DFF=4096
// R1: XOR-swizzle all attention LDS tiles (K via pre-swizzled gload_lds source,
//     V^T and P via swizzled scatter/read). Pre-scale q by 1/8 in QKV epilogue.

#define D_MODEL 1024
#define D_FF    4096
#define NH      16
#define BATCH   4
#define SEQ     2048
#define DK      64
#define MTOK    (BATCH*SEQ)   // 8192
#define NBH     (BATCH*NH)    // 64

typedef __bf16 bf16;
typedef bf16  bf16x4 __attribute__((ext_vector_type(4)));
typedef bf16  bf16x8 __attribute__((ext_vector_type(8)));
typedef float f32x4  __attribute__((ext_vector_type(4)));

__device__ __forceinline__ void gload_lds16(const bf16* g, bf16* l) {
  __builtin_amdgcn_global_load_lds(
      (__attribute__((address_space(1))) void*)g,
      (__attribute__((address_space(3))) void*)l, 16, 0, 0);
}

// Swizzled element offset in a [rows][64 bf16] LDS tile (128B rows, 16B granules):
// granule column ^= (row & 7).  Involution; conflict-free for row-varying b128 reads.
__device__ __forceinline__ int swz64(int row, int col) {
  return (row << 6) + ((((col >> 3) ^ (row & 7)) << 3) | (col & 7));
}

// ---------------- fp32 -> bf16 cast (weights) ----------------
__global__ __launch_bounds__(256) void cast_w(const float* __restrict__ s,
                                              bf16* __restrict__ d, int n) {
  int i = (blockIdx.x * 256 + threadIdx.x) * 4;
  if (i >= n) return;
  float4 v = *(const float4*)(s + i);
  bf16x4 o;
  o[0] = (bf16)v.x; o[1] = (bf16)v.y; o[2] = (bf16)v.z; o[3] = (bf16)v.w;
  *(bf16x4*)(d + i) = o;
}

// ---------------- LayerNorm (fp32 in, bf16 out) ----------------
__global__ __launch_bounds__(256) void ln_kernel(const float* __restrict__ x,
                                                 const float* __restrict__ g,
                                                 const float* __restrict__ b,
                                                 bf16* __restrict__ out) {
  int row = blockIdx.x;
  int tid = threadIdx.x;
  const float* xr = x + (size_t)row * D_MODEL;
  float4 v = *(const float4*)(xr + tid * 4);
  float s  = v.x + v.y + v.z + v.w;
  float sq = v.x*v.x + v.y*v.y + v.z*v.z + v.w*v.w;
  #pragma unroll
  for (int off = 1; off < 64; off <<= 1) {
    s  += __shfl_xor(s,  off, 64);
    sq += __shfl_xor(sq, off, 64);
  }
  __shared__ float ls[4], lq[4];
  int wid = tid >> 6, lane = tid & 63;
  if (lane == 0) { ls[wid] = s; lq[wid] = sq; }
  __syncthreads();
  s  = ls[0] + ls[1] + ls[2] + ls[3];
  sq = lq[0] + lq[1] + lq[2] + lq[3];
  float mu   = s * (1.0f / D_MODEL);
  float var  = sq * (1.0f / D_MODEL) - mu * mu;
  float rstd = rsqrtf(var + 1e-5f);
  float4 gv = *(const float4*)(g + tid * 4);
  float4 bv = *(const float4*)(b + tid * 4);
  bf16x4 o;
  o[0] = (bf16)((v.x - mu) * rstd * gv.x + bv.x);
  o[1] = (bf16)((v.y - mu) * rstd * gv.y + bv.y);
  o[2] = (bf16)((v.z - mu) * rstd * gv.z + bv.z);
  o[3] = (bf16)((v.w - mu) * rstd * gv.w + bv.w);
  *(bf16x4*)(out + (size_t)row * D_MODEL + tid * 4) = o;
}

// ---------------- GEMM: C[M,N] = A[M,K] @ W[N,K]^T (+bias, epilogue) --------
// 128x128 tile, BK=64, 4 waves (2x2), 16x16x32 bf16 MFMA (m97 structure).
enum { EP_QKV = 0, EP_RESID = 1, EP_GELU = 2 };

template <int EP>
__global__ __launch_bounds__(256) void gemm_bt(
    const bf16* __restrict__ A, const bf16* __restrict__ W,
    const float* __restrict__ bias,
    const float* __restrict__ resid,   // EP_RESID: fp32 residual input
    float* __restrict__ out_f32,       // EP_RESID dst
    bf16* __restrict__ out_bf,         // EP_QKV: qkv base [3][BH][T][DK]; EP_GELU: [M,N]
    int M, int N, int K) {
  __shared__ bf16 lA[128 * 64];
  __shared__ bf16 lB[128 * 64];
  int tiles_n = N >> 7;
  int bm = blockIdx.x / tiles_n, bn = blockIdx.x % tiles_n;
  int m0 = bm << 7, n0 = bn << 7;
  int tid = threadIdx.x, wid = tid >> 6, lane = tid & 63;
  int wm = wid >> 1, wn = wid & 1;
  int l15 = lane & 15, l4 = lane >> 4;

  f32x4 acc[4][4];
  #pragma unroll
  for (int i = 0; i < 4; i++)
    #pragma unroll
    for (int n = 0; n < 4; n++)
      #pragma unroll
      for (int e = 0; e < 4; e++) acc[i][n][e] = 0.f;

  int rA = tid >> 3;           // 0..31
  int c8 = (tid & 7) << 3;     // 0..56
  const bf16* gA = A + (size_t)(m0 + rA) * K + c8;
  const bf16* gW = W + (size_t)(n0 + rA) * K + c8;
  bf16* lAbase = lA + (wid << 9);
  bf16* lBbase = lB + (wid << 9);

  for (int kt = 0; kt < K; kt += 64) {
    __syncthreads();
    #pragma unroll
    for (int it = 0; it < 4; ++it) {
      gload_lds16(gA + (size_t)(it * 32) * K + kt, lAbase + it * 2048);
      gload_lds16(gW + (size_t)(it * 32) * K + kt, lBbase + it * 2048);
    }
    __syncthreads();
    #pragma unroll
    for (int kk = 0; kk < 2; ++kk) {
      bf16x8 af[4], bfr[4];
      #pragma unroll
      for (int i = 0; i < 4; i++) {
        af[i]  = *(const bf16x8*)(lA + (wm * 64 + i * 16 + l15) * 64 + kk * 32 + (l4 << 3));
        bfr[i] = *(const bf16x8*)(lB + (wn * 64 + i * 16 + l15) * 64 + kk * 32 + (l4 << 3));
      }
      #pragma unroll
      for (int i = 0; i < 4; i++)
        #pragma unroll
        for (int n = 0; n < 4; n++)
          acc[i][n] = __builtin_amdgcn_mfma_f32_16x16x32_bf16(af[i], bfr[n], acc[i][n], 0, 0, 0);
    }
  }

  #pragma unroll
  for (int i = 0; i < 4; i++)
    #pragma unroll
    for (int n = 0; n < 4; n++)
      #pragma unroll
      for (int j = 0; j < 4; j++) {
        int gm = m0 + wm * 64 + i * 16 + (l4 << 2) + j;
        int gn = n0 + wn * 64 + n * 16 + l15;
        float cv = acc[i][n][j] + bias[gn];
        if (EP == EP_QKV) {
          int which = gn >> 10;          // 0=q 1=k 2=v
          int nn = gn & 1023;
          int head = nn >> 6, d = nn & 63;
          int bb = gm >> 11, t = gm & 2047;
          if (which == 0) cv *= 0.125f;  // pre-apply 1/sqrt(dk) to q
          size_t idx = (size_t)which * (NBH * SEQ * DK) +
                       ((size_t)(bb * NH + head) * SEQ + t) * DK + d;
          out_bf[idx] = (bf16)cv;
        } else if (EP == EP_RESID) {
          size_t idx = (size_t)gm * N + gn;
          out_f32[idx] = resid[idx] + cv;
        } else {  // EP_GELU (exact erf)
          float ge = 0.5f * cv * (1.0f + erff(cv * 0.70710678118654752f));
          out_bf[(size_t)gm * N + gn] = (bf16)ge;
        }
      }
}

// ---------------- Flash attention ----------------
// grid: (T/64) * BH blocks, 256 thr. Wave w owns 16 q-rows. KVBLK=64.
// q,k,v: [BH][T][DK] bf16 (q pre-scaled by 1/8).  o: [B][T][D_MODEL] bf16.
// All LDS tiles XOR-swizzled (swz64) to kill 16-way ds_read_b128 conflicts.
__global__ __launch_bounds__(256) void attn_kernel(
    const bf16* __restrict__ q, const bf16* __restrict__ k,
    const bf16* __restrict__ v, bf16* __restrict__ o) {
  __shared__ bf16 kt_lds[64 * 64];      // K tile [kv][d], swizzled
  __shared__ bf16 vt_lds[64 * 64];      // V^T tile [d][kv], swizzled
  __shared__ bf16 p_lds[4][16 * 64];    // per-wave P [qrow][kv], swizzled
  int bid = blockIdx.x;
  int bh = bid >> 5;                     // T/64 = 32 q-tiles
  int qt = bid & 31;
  int t0 = qt << 6;
  int tid = threadIdx.x, wid = tid >> 6, lane = tid & 63;
  int l15 = lane & 15, l4 = lane >> 4;

  // Q fragments (A-operand): rows t0 + wid*16 + l15
  const bf16* qbase = q + ((size_t)bh * SEQ + t0 + wid * 16 + l15) * DK;
  bf16x8 qf[2];
  qf[0] = *(const bf16x8*)(qbase + (l4 << 3));
  qf[1] = *(const bf16x8*)(qbase + 32 + (l4 << 3));

  float m_run[4], l_run[4];
  f32x4 acc_o[4];
  #pragma unroll
  for (int j = 0; j < 4; j++) { m_run[j] = -1e30f; l_run[j] = 0.f; }
  #pragma unroll
  for (int n = 0; n < 4; n++)
    #pragma unroll
    for (int e = 0; e < 4; e++) acc_o[n][e] = 0.f;

  // K staging: linear LDS dest; source column pre-swizzled (inverse XOR).
  int rK = tid >> 3;
  int cKs = (((tid & 7) ^ (rK & 7)) << 3);
  const bf16* gK = k + ((size_t)bh * SEQ + rK) * DK + cKs;
  bf16* lKbase = kt_lds + (wid << 9);
  int rV = tid >> 2, cV = (tid & 3) << 4;
  const bf16* gV = v + ((size_t)bh * SEQ + rV) * DK + cV;

  for (int kv0 = 0; kv0 < SEQ; kv0 += 64) {
    __syncthreads();
    #pragma unroll
    for (int it = 0; it < 2; ++it)
      gload_lds16(gK + (size_t)(kv0 + it * 32) * DK, lKbase + it * 2048);
    bf16x8 v0 = *(const bf16x8*)(gV + (size_t)kv0 * DK);
    bf16x8 v1 = *(const bf16x8*)(gV + (size_t)kv0 * DK + 8);
    #pragma unroll
    for (int jj = 0; jj < 8; jj++) {
      vt_lds[swz64(cV + jj,     rV)] = v0[jj];
      vt_lds[swz64(cV + 8 + jj, rV)] = v1[jj];
    }
    __syncthreads();

    // S = Q K^T  (q pre-scaled by 1/8)
    f32x4 accs[4];
    #pragma unroll
    for (int n = 0; n < 4; n++) {
      #pragma unroll
      for (int e = 0; e < 4; e++) accs[n][e] = 0.f;
      #pragma unroll
      for (int kk = 0; kk < 2; kk++) {
        bf16x8 kf = *(const bf16x8*)(kt_lds + swz64(n * 16 + l15, kk * 32 + (l4 << 3)));
        accs[n] = __builtin_amdgcn_mfma_f32_16x16x32_bf16(qf[kk], kf, accs[n], 0, 0, 0);
      }
    }
    // online softmax per owned row j (row = l4*4+j), reduce across 16 lanes
    float p[4][4];
    #pragma unroll
    for (int j = 0; j < 4; j++) {
      float mx = -1e30f;
      #pragma unroll
      for (int n = 0; n < 4; n++) mx = fmaxf(mx, accs[n][j]);
      #pragma unroll
      for (int off = 1; off < 16; off <<= 1) mx = fmaxf(mx, __shfl_xor(mx, off, 64));
      float mn = fmaxf(m_run[j], mx);
      float sc = __expf(m_run[j] - mn);
      m_run[j] = mn;
      float rs = 0.f;
      #pragma unroll
      for (int n = 0; n < 4; n++) { float pv = __expf(accs[n][j] - mn); p[n][j] = pv; rs += pv; }
      #pragma unroll
      for (int off = 1; off < 16; off <<= 1) rs += __shfl_xor(rs, off, 64);
      l_run[j] = l_run[j] * sc + rs;
      #pragma unroll
      for (int n = 0; n < 4; n++) acc_o[n][j] *= sc;
    }
    // P: D-layout -> LDS (swizzled) -> A-layout
    #pragma unroll
    for (int j = 0; j < 4; j++)
      #pragma unroll
      for (int n = 0; n < 4; n++)
        p_lds[wid][swz64(l4 * 4 + j, n * 16 + l15)] = (bf16)p[n][j];
    #pragma unroll
    for (int kk = 0; kk < 2; kk++) {
      bf16x8 pa = *(const bf16x8*)(&p_lds[wid][swz64(l15, kk * 32 + (l4 << 3))]);
      #pragma unroll
      for (int nd = 0; nd < 4; nd++) {
        bf16x8 vf = *(const bf16x8*)(vt_lds + swz64(nd * 16 + l15, kk * 32 + (l4 << 3)));
        acc_o[nd] = __builtin_amdgcn_mfma_f32_16x16x32_bf16(pa, vf, acc_o[nd], 0, 0, 0);
      }
    }
  }
  int bb = bh >> 4, hh = bh & 15;
  #pragma unroll
  for (int nd = 0; nd < 4; nd++)
    #pragma unroll
    for (int j = 0; j < 4; j++) {
      int row = t0 + wid * 16 + l4 * 4 + j;
      int d = nd * 16 + l15;
      float ov = acc_o[nd][j] / l_run[j];
      o[((size_t)bb * SEQ + row) * D_MODEL + hh * DK + d] = (bf16)ov;
    }
}

// ---------------- launch ----------------
extern "C" void kernel_launch(void* const* d_in, const int* in_sizes, int n_in,
                              void* d_out, int out_size, void* d_ws, size_t ws_size,
                              hipStream_t stream) {
  const float* x    = (const float*)d_in[0];
  const float* ln1g = (const float*)d_in[1];
  const float* ln1b = (const float*)d_in[2];
  const float* wq   = (const float*)d_in[3];
  const float* bq   = (const float*)d_in[4];
  const float* wk   = (const float*)d_in[5];
  const float* bk   = (const float*)d_in[6];
  const float* wv   = (const float*)d_in[7];
  const float* bv   = (const float*)d_in[8];
  const float* wo   = (const float*)d_in[9];
  const float* bo   = (const float*)d_in[10];
  const float* ln2g = (const float*)d_in[11];
  const float* ln2b = (const float*)d_in[12];
  const float* w1   = (const float*)d_in[13];
  const float* b1   = (const float*)d_in[14];
  const float* w2   = (const float*)d_in[15];
  const float* b2   = (const float*)d_in[16];
  float* out = (float*)d_out;

  char* ws = (char*)d_ws;
  bf16* wqkv_b = (bf16*)(ws);                          // [3072,1024]  6MB
  bf16* wo_b   = (bf16*)(ws + ((size_t)6  << 20));     // 2MB
  bf16* w1_b   = (bf16*)(ws + ((size_t)8  << 20));     // 8MB
  bf16* w2_b   = (bf16*)(ws + ((size_t)16 << 20));     // 8MB
  bf16* h_b    = (bf16*)(ws + ((size_t)24 << 20));     // 16MB (h, later h2)
  bf16* qkv_b  = (bf16*)(ws + ((size_t)40 << 20));     // 48MB q|k|v
  bf16* o_b    = (bf16*)(ws + ((size_t)88 << 20));     // 16MB
  bf16* ffn1_b = (bf16*)(ws + ((size_t)40 << 20));     // 64MB (over dead q,k,v,o)
  float* bqkv  = (float*)(ws + ((size_t)104 << 20));   // 12KB

  cast_w<<<1024, 256, 0, stream>>>(wq, wqkv_b, 1 << 20);
  cast_w<<<1024, 256, 0, stream>>>(wk, wqkv_b + (1 << 20), 1 << 20);
  cast_w<<<1024, 256, 0, stream>>>(wv, wqkv_b + (2 << 20), 1 << 20);
  cast_w<<<1024, 256, 0, stream>>>(wo, wo_b, 1 << 20);
  cast_w<<<4096, 256, 0, stream>>>(w1, w1_b, 1 << 22);
  cast_w<<<4096, 256, 0, stream>>>(w2, w2_b, 1 << 22);
  hipMemcpyAsync(bqkv,        bq, 4096, hipMemcpyDeviceToDevice, stream);
  hipMemcpyAsync(bqkv + 1024, bk, 4096, hipMemcpyDeviceToDevice, stream);
  hipMemcpyAsync(bqkv + 2048, bv, 4096, hipMemcpyDeviceToDevice, stream);

  ln_kernel<<<MTOK, 256, 0, stream>>>(x, ln1g, ln1b, h_b);
  gemm_bt<EP_QKV><<<64 * 24, 256, 0, stream>>>(h_b, wqkv_b, bqkv, nullptr, nullptr,
                                               qkv_b, MTOK, 3072, 1024);
  attn_kernel<<<NBH * 32, 256, 0, stream>>>(qkv_b, qkv_b + (size_t)NBH * SEQ * DK,
                                            qkv_b + (size_t)2 * NBH * SEQ * DK, o_b);
  gemm_bt<EP_RESID><<<64 * 8, 256, 0, stream>>>(o_b, wo_b, bo, x, out, nullptr,
                                                MTOK, 1024, 1024);
  ln_kernel<<<MTOK, 256, 0, stream>>>(out, ln2g, ln2b, h_b);
  gemm_bt<EP_GELU><<<64 * 32, 256, 0, stream>>>(h_b, w1_b, b1, nullptr, nullptr,
                                                ffn1_b, MTOK, 4096, 1024);
  gemm_bt<EP_RESID><<<64 * 8, 256, 0, stream>>>(ffn1_b, w2_b, b2, out, out, nullptr,
                                                MTOK, 1024, 4096);
}

// Round 3
// 561.431 us; speedup vs baseline: 1.2443x; 1.1053x over previous
//
#include <hip/hip_runtime.h>
#include <math.h>

// EncoderBlock: pre-LN attention + FFN, bf16 MFMA compute, fp32 residual spine.
// B=4 T=2048 D=1024 H=16 dk=64 DFF=4096
// R1: XOR-swizzle attn LDS tiles; q pre-scaled.
// R2: V transposed in QKV epilogue (vT[bh][d][t], packed bf16x4) -> staged via
//     global_load_lds; KVBLK=128; exp2-domain softmax (q pre-scaled by
//     0.125*log2e); T13 defer-max (thr=8).

#define D_MODEL 1024
#define D_FF    4096
#define NH      16
#define BATCH   4
#define SEQ     2048
#define DK      64
#define MTOK    (BATCH*SEQ)   // 8192
#define NBH     (BATCH*NH)    // 64

typedef __bf16 bf16;
typedef bf16  bf16x4 __attribute__((ext_vector_type(4)));
typedef bf16  bf16x8 __attribute__((ext_vector_type(8)));
typedef float f32x4  __attribute__((ext_vector_type(4)));

__device__ __forceinline__ void gload_lds16(const bf16* g, bf16* l) {
  __builtin_amdgcn_global_load_lds(
      (__attribute__((address_space(1))) void*)g,
      (__attribute__((address_space(3))) void*)l, 16, 0, 0);
}

// ---------------- fp32 -> bf16 cast (weights) ----------------
__global__ __launch_bounds__(256) void cast_w(const float* __restrict__ s,
                                              bf16* __restrict__ d, int n) {
  int i = (blockIdx.x * 256 + threadIdx.x) * 4;
  if (i >= n) return;
  float4 v = *(const float4*)(s + i);
  bf16x4 o;
  o[0] = (bf16)v.x; o[1] = (bf16)v.y; o[2] = (bf16)v.z; o[3] = (bf16)v.w;
  *(bf16x4*)(d + i) = o;
}

// ---------------- LayerNorm (fp32 in, bf16 out) ----------------
__global__ __launch_bounds__(256) void ln_kernel(const float* __restrict__ x,
                                                 const float* __restrict__ g,
                                                 const float* __restrict__ b,
                                                 bf16* __restrict__ out) {
  int row = blockIdx.x;
  int tid = threadIdx.x;
  const float* xr = x + (size_t)row * D_MODEL;
  float4 v = *(const float4*)(xr + tid * 4);
  float s  = v.x + v.y + v.z + v.w;
  float sq = v.x*v.x + v.y*v.y + v.z*v.z + v.w*v.w;
  #pragma unroll
  for (int off = 1; off < 64; off <<= 1) {
    s  += __shfl_xor(s,  off, 64);
    sq += __shfl_xor(sq, off, 64);
  }
  __shared__ float ls[4], lq[4];
  int wid = tid >> 6, lane = tid & 63;
  if (lane == 0) { ls[wid] = s; lq[wid] = sq; }
  __syncthreads();
  s  = ls[0] + ls[1] + ls[2] + ls[3];
  sq = lq[0] + lq[1] + lq[2] + lq[3];
  float mu   = s * (1.0f / D_MODEL);
  float var  = sq * (1.0f / D_MODEL) - mu * mu;
  float rstd = rsqrtf(var + 1e-5f);
  float4 gv = *(const float4*)(g + tid * 4);
  float4 bv = *(const float4*)(b + tid * 4);
  bf16x4 o;
  o[0] = (bf16)((v.x - mu) * rstd * gv.x + bv.x);
  o[1] = (bf16)((v.y - mu) * rstd * gv.y + bv.y);
  o[2] = (bf16)((v.z - mu) * rstd * gv.z + bv.z);
  o[3] = (bf16)((v.w - mu) * rstd * gv.w + bv.w);
  *(bf16x4*)(out + (size_t)row * D_MODEL + tid * 4) = o;
}

// ---------------- GEMM: C[M,N] = A[M,K] @ W[N,K]^T (+bias, epilogue) --------
// 128x128 tile, BK=64, 4 waves (2x2), 16x16x32 bf16 MFMA (m97 structure).
enum { EP_QKV = 0, EP_RESID = 1, EP_GELU = 2 };

#define QSCALE 0.18033688011112042f  // (1/8) * log2(e)

template <int EP>
__global__ __launch_bounds__(256) void gemm_bt(
    const bf16* __restrict__ A, const bf16* __restrict__ W,
    const float* __restrict__ bias,
    const float* __restrict__ resid,   // EP_RESID: fp32 residual input
    float* __restrict__ out_f32,       // EP_RESID dst
    bf16* __restrict__ out_bf,         // EP_QKV: qkv base; EP_GELU: [M,N]
    int M, int N, int K) {
  __shared__ bf16 lA[128 * 64];
  __shared__ bf16 lB[128 * 64];
  int tiles_n = N >> 7;
  int bm = blockIdx.x / tiles_n, bn = blockIdx.x % tiles_n;
  int m0 = bm << 7, n0 = bn << 7;
  int tid = threadIdx.x, wid = tid >> 6, lane = tid & 63;
  int wm = wid >> 1, wn = wid & 1;
  int l15 = lane & 15, l4 = lane >> 4;

  f32x4 acc[4][4];
  #pragma unroll
  for (int i = 0; i < 4; i++)
    #pragma unroll
    for (int n = 0; n < 4; n++)
      #pragma unroll
      for (int e = 0; e < 4; e++) acc[i][n][e] = 0.f;

  int rA = tid >> 3;           // 0..31
  int c8 = (tid & 7) << 3;     // 0..56
  const bf16* gA = A + (size_t)(m0 + rA) * K + c8;
  const bf16* gW = W + (size_t)(n0 + rA) * K + c8;
  bf16* lAbase = lA + (wid << 9);
  bf16* lBbase = lB + (wid << 9);

  for (int kt = 0; kt < K; kt += 64) {
    __syncthreads();
    #pragma unroll
    for (int it = 0; it < 4; ++it) {
      gload_lds16(gA + (size_t)(it * 32) * K + kt, lAbase + it * 2048);
      gload_lds16(gW + (size_t)(it * 32) * K + kt, lBbase + it * 2048);
    }
    __syncthreads();
    #pragma unroll
    for (int kk = 0; kk < 2; ++kk) {
      bf16x8 af[4], bfr[4];
      #pragma unroll
      for (int i = 0; i < 4; i++) {
        af[i]  = *(const bf16x8*)(lA + (wm * 64 + i * 16 + l15) * 64 + kk * 32 + (l4 << 3));
        bfr[i] = *(const bf16x8*)(lB + (wn * 64 + i * 16 + l15) * 64 + kk * 32 + (l4 << 3));
      }
      #pragma unroll
      for (int i = 0; i < 4; i++)
        #pragma unroll
        for (int n = 0; n < 4; n++)
          acc[i][n] = __builtin_amdgcn_mfma_f32_16x16x32_bf16(af[i], bfr[n], acc[i][n], 0, 0, 0);
    }
  }

  if (EP == EP_QKV) {
    #pragma unroll
    for (int i = 0; i < 4; i++)
      #pragma unroll
      for (int n = 0; n < 4; n++) {
        int gm0 = m0 + wm * 64 + i * 16 + (l4 << 2);   // 4 consecutive tokens
        int gn  = n0 + wn * 64 + n * 16 + l15;
        int which = gn >> 10;            // 0=q 1=k 2=v (uniform per 16-run)
        int nn = gn & 1023, head = nn >> 6, d = nn & 63;
        int bb = gm0 >> 11, t = gm0 & 2047;
        float bv = bias[gn];
        if (which == 2) {
          // V transposed: vT[bh][d][t], 4 t's packed
          bf16x4 pk;
          #pragma unroll
          for (int j = 0; j < 4; j++) pk[j] = (bf16)(acc[i][n][j] + bv);
          *(bf16x4*)(out_bf + (size_t)2 * NBH * SEQ * DK +
                     ((size_t)(bb * NH + head) * DK + d) * SEQ + t) = pk;
        } else {
          float scale = (which == 0) ? QSCALE : 1.0f;
          #pragma unroll
          for (int j = 0; j < 4; j++) {
            float cv = (acc[i][n][j] + bv) * scale;
            size_t idx = (size_t)which * (NBH * SEQ * DK) +
                         ((size_t)(bb * NH + head) * SEQ + (t + j)) * DK + d;
            out_bf[idx] = (bf16)cv;
          }
        }
      }
  } else {
    #pragma unroll
    for (int i = 0; i < 4; i++)
      #pragma unroll
      for (int n = 0; n < 4; n++)
        #pragma unroll
        for (int j = 0; j < 4; j++) {
          int gm = m0 + wm * 64 + i * 16 + (l4 << 2) + j;
          int gn = n0 + wn * 64 + n * 16 + l15;
          float cv = acc[i][n][j] + bias[gn];
          if (EP == EP_RESID) {
            size_t idx = (size_t)gm * N + gn;
            out_f32[idx] = resid[idx] + cv;
          } else {  // EP_GELU (exact erf)
            float ge = 0.5f * cv * (1.0f + erff(cv * 0.70710678118654752f));
            out_bf[(size_t)gm * N + gn] = (bf16)ge;
          }
        }
  }
}

// ---------------- Flash attention ----------------
// grid: (T/64)*BH blocks, 256 thr, 4 waves x 16 q-rows. KVBLK=128.
// q: [BH][T][DK] pre-scaled by 0.125*log2e; k: [BH][T][DK]; vt: [BH][DK][T].
// o: [B][T][D_MODEL] bf16. Softmax in log2 domain with defer-max (thr=8).
__global__ __launch_bounds__(256) void attn_kernel(
    const bf16* __restrict__ q, const bf16* __restrict__ k,
    const bf16* __restrict__ vt, bf16* __restrict__ o) {
  __shared__ bf16 kt_lds[128 * 64];     // [kv][d], granule ^= row&7
  __shared__ bf16 vt_lds[64 * 128];     // [d][kv], granule ^= row&15
  __shared__ bf16 p_lds[4][16 * 128];   // per-wave [q][kv], granule ^= row
  int bid = blockIdx.x;
  int bh = bid >> 5;                     // 32 q-tiles of 64 rows
  int qt = bid & 31;
  int t0 = qt << 6;
  int tid = threadIdx.x, wid = tid >> 6, lane = tid & 63;
  int l15 = lane & 15, l4 = lane >> 4;

  const bf16* qbase = q + ((size_t)bh * SEQ + t0 + wid * 16 + l15) * DK;
  bf16x8 qf[2];
  qf[0] = *(const bf16x8*)(qbase + (l4 << 3));
  qf[1] = *(const bf16x8*)(qbase + 32 + (l4 << 3));

  float m_run[4], l_run[4];
  f32x4 acc_o[4];
  #pragma unroll
  for (int j = 0; j < 4; j++) { m_run[j] = -1e30f; l_run[j] = 0.f; }
  #pragma unroll
  for (int nd = 0; nd < 4; nd++)
    #pragma unroll
    for (int e = 0; e < 4; e++) acc_o[nd][e] = 0.f;

  // K staging: linear dest, inverse-swizzled source column (granule ^= row&7)
  int rK = tid >> 3;                       // 0..31 per issue
  int cK = ((tid & 7) ^ (rK & 7)) << 3;
  const bf16* gK = k + ((size_t)bh * SEQ + rK) * DK + cK;
  bf16* lK = kt_lds + (wid << 9);
  // V^T staging: rows d, 256B rows, inverse-swizzled (granule ^= row&15)
  int rV = tid >> 4;                       // 0..15 per issue
  int cV = ((tid & 15) ^ (rV & 15)) << 3;
  const bf16* gV = vt + ((size_t)bh * DK + rV) * SEQ + cV;
  bf16* lV = vt_lds + (wid << 9);
  bf16* pw = p_lds[wid];

  for (int kv0 = 0; kv0 < SEQ; kv0 += 128) {
    __syncthreads();
    #pragma unroll
    for (int it = 0; it < 4; ++it) {
      gload_lds16(gK + (size_t)(kv0 + it * 32) * DK, lK + it * 2048);
      gload_lds16(gV + (size_t)it * 16 * SEQ + kv0, lV + it * 2048);
    }
    __syncthreads();

    // S^... = Q K^T, 8 col-tiles of 16 kv
    f32x4 accs[8];
    #pragma unroll
    for (int n = 0; n < 8; n++) {
      #pragma unroll
      for (int e = 0; e < 4; e++) accs[n][e] = 0.f;
      #pragma unroll
      for (int kk = 0; kk < 2; kk++) {
        int rowk = n * 16 + l15;
        bf16x8 kf = *(const bf16x8*)(kt_lds + rowk * 64 + (((kk * 4 + l4) ^ (rowk & 7)) << 3));
        accs[n] = __builtin_amdgcn_mfma_f32_16x16x32_bf16(qf[kk], kf, accs[n], 0, 0, 0);
      }
    }

    // online softmax, log2 domain; q row = l4*4+j
    float mx[4];
    #pragma unroll
    for (int j = 0; j < 4; j++) {
      float a0 = fmaxf(fmaxf(accs[0][j], accs[1][j]), fmaxf(accs[2][j], accs[3][j]));
      float a1 = fmaxf(fmaxf(accs[4][j], accs[5][j]), fmaxf(accs[6][j], accs[7][j]));
      float v = fmaxf(a0, a1);
      #pragma unroll
      for (int off = 1; off < 16; off <<= 1) v = fmaxf(v, __shfl_xor(v, off, 64));
      mx[j] = v;
    }
    bool need = false;
    #pragma unroll
    for (int j = 0; j < 4; j++) need = need || (mx[j] > m_run[j] + 8.0f);
    if (__any(need)) {
      #pragma unroll
      for (int j = 0; j < 4; j++) {
        float mn = fmaxf(m_run[j], mx[j]);
        float sc = exp2f(m_run[j] - mn);
        m_run[j] = mn;
        l_run[j] *= sc;
        #pragma unroll
        for (int nd = 0; nd < 4; nd++) acc_o[nd][j] *= sc;
      }
    }
    #pragma unroll
    for (int j = 0; j < 4; j++) {
      int row = l4 * 4 + j;
      float rs = 0.f;
      #pragma unroll
      for (int n = 0; n < 8; n++) {
        float pv = exp2f(accs[n][j] - m_run[j]);
        rs += pv;
        int gcol = (2 * n + (l15 >> 3)) ^ row;       // granule ^= row (row<16)
        pw[row * 128 + (gcol << 3) + (l15 & 7)] = (bf16)pv;
      }
      #pragma unroll
      for (int off = 1; off < 16; off <<= 1) rs += __shfl_xor(rs, off, 64);
      l_run[j] += rs;
    }

    // O += P @ V  (A = P rows q=l15, B = V^T rows d)
    #pragma unroll
    for (int kk = 0; kk < 4; kk++) {
      bf16x8 pa = *(const bf16x8*)(pw + l15 * 128 + (((kk * 4 + l4) ^ l15) << 3));
      #pragma unroll
      for (int nd = 0; nd < 4; nd++) {
        int rowv = nd * 16 + l15;
        bf16x8 vf = *(const bf16x8*)(vt_lds + rowv * 128 + (((kk * 4 + l4) ^ l15) << 3));
        acc_o[nd] = __builtin_amdgcn_mfma_f32_16x16x32_bf16(pa, vf, acc_o[nd], 0, 0, 0);
      }
    }
  }
  int bb = bh >> 4, hh = bh & 15;
  #pragma unroll
  for (int nd = 0; nd < 4; nd++)
    #pragma unroll
    for (int j = 0; j < 4; j++) {
      int row = t0 + wid * 16 + l4 * 4 + j;
      int d = nd * 16 + l15;
      float ov = acc_o[nd][j] / l_run[j];
      o[((size_t)bb * SEQ + row) * D_MODEL + hh * DK + d] = (bf16)ov;
    }
}

// ---------------- launch ----------------
extern "C" void kernel_launch(void* const* d_in, const int* in_sizes, int n_in,
                              void* d_out, int out_size, void* d_ws, size_t ws_size,
                              hipStream_t stream) {
  const float* x    = (const float*)d_in[0];
  const float* ln1g = (const float*)d_in[1];
  const float* ln1b = (const float*)d_in[2];
  const float* wq   = (const float*)d_in[3];
  const float* bq   = (const float*)d_in[4];
  const float* wk   = (const float*)d_in[5];
  const float* bk   = (const float*)d_in[6];
  const float* wv   = (const float*)d_in[7];
  const float* bv   = (const float*)d_in[8];
  const float* wo   = (const float*)d_in[9];
  const float* bo   = (const float*)d_in[10];
  const float* ln2g = (const float*)d_in[11];
  const float* ln2b = (const float*)d_in[12];
  const float* w1   = (const float*)d_in[13];
  const float* b1   = (const float*)d_in[14];
  const float* w2   = (const float*)d_in[15];
  const float* b2   = (const float*)d_in[16];
  float* out = (float*)d_out;

  char* ws = (char*)d_ws;
  bf16* wqkv_b = (bf16*)(ws);                          // [3072,1024]  6MB
  bf16* wo_b   = (bf16*)(ws + ((size_t)6  << 20));     // 2MB
  bf16* w1_b   = (bf16*)(ws + ((size_t)8  << 20));     // 8MB
  bf16* w2_b   = (bf16*)(ws + ((size_t)16 << 20));     // 8MB
  bf16* h_b    = (bf16*)(ws + ((size_t)24 << 20));     // 16MB (h, later h2)
  bf16* qkv_b  = (bf16*)(ws + ((size_t)40 << 20));     // 48MB q|k|vT
  bf16* o_b    = (bf16*)(ws + ((size_t)88 << 20));     // 16MB
  bf16* ffn1_b = (bf16*)(ws + ((size_t)40 << 20));     // 64MB (over dead q,k,v,o)
  float* bqkv  = (float*)(ws + ((size_t)104 << 20));   // 12KB

  cast_w<<<1024, 256, 0, stream>>>(wq, wqkv_b, 1 << 20);
  cast_w<<<1024, 256, 0, stream>>>(wk, wqkv_b + (1 << 20), 1 << 20);
  cast_w<<<1024, 256, 0, stream>>>(wv, wqkv_b + (2 << 20), 1 << 20);
  cast_w<<<1024, 256, 0, stream>>>(wo, wo_b, 1 << 20);
  cast_w<<<4096, 256, 0, stream>>>(w1, w1_b, 1 << 22);
  cast_w<<<4096, 256, 0, stream>>>(w2, w2_b, 1 << 22);
  hipMemcpyAsync(bqkv,        bq, 4096, hipMemcpyDeviceToDevice, stream);
  hipMemcpyAsync(bqkv + 1024, bk, 4096, hipMemcpyDeviceToDevice, stream);
  hipMemcpyAsync(bqkv + 2048, bv, 4096, hipMemcpyDeviceToDevice, stream);

  ln_kernel<<<MTOK, 256, 0, stream>>>(x, ln1g, ln1b, h_b);
  gemm_bt<EP_QKV><<<64 * 24, 256, 0, stream>>>(h_b, wqkv_b, bqkv, nullptr, nullptr,
                                               qkv_b, MTOK, 3072, 1024);
  attn_kernel<<<NBH * 32, 256, 0, stream>>>(qkv_b, qkv_b + (size_t)NBH * SEQ * DK,
                                            qkv_b + (size_t)2 * NBH * SEQ * DK, o_b);
  gemm_bt<EP_RESID><<<64 * 8, 256, 0, stream>>>(o_b, wo_b, bo, x, out, nullptr,
                                                MTOK, 1024, 1024);
  ln_kernel<<<MTOK, 256, 0, stream>>>(out, ln2g, ln2b, h_b);
  gemm_bt<EP_GELU><<<64 * 32, 256, 0, stream>>>(h_b, w1_b, b1, nullptr, nullptr,
                                                ffn1_b, MTOK, 4096, 1024);
  gemm_bt<EP_RESID><<<64 * 8, 256, 0, stream>>>(ffn1_b, w2_b, b2, out, out, nullptr,
                                                MTOK, 1024, 4096);
}

// Round 4
// 524.762 us; speedup vs baseline: 1.3312x; 1.0699x over previous
//
#include <hip/hip_runtime.h>
#include <math.h>

// EncoderBlock: pre-LN attention + FFN, bf16 MFMA compute, fp32 residual spine.
// B=4 T=2048 D=1024 H=16 dk=64 DFF=4096
// R1: XOR-swizzle attn LDS tiles; q pre-scaled.
// R2: V^T staged via global_load_lds; KVBLK=128; exp2-domain softmax; defer-max.
// R3: swapped QK^T (mfma(K,Q)) -> lane-local P rows; PV via 16x16x16 f16 mfma
//     reusing P registers directly (no LDS P round-trip); V/P in fp16.

#define D_MODEL 1024
#define D_FF    4096
#define NH      16
#define BATCH   4
#define SEQ     2048
#define DK      64
#define MTOK    (BATCH*SEQ)   // 8192
#define NBH     (BATCH*NH)    // 64

typedef __bf16 bf16;
typedef _Float16 f16;
typedef bf16  bf16x4 __attribute__((ext_vector_type(4)));
typedef bf16  bf16x8 __attribute__((ext_vector_type(8)));
typedef f16   f16x4  __attribute__((ext_vector_type(4)));
typedef float f32x4  __attribute__((ext_vector_type(4)));

__device__ __forceinline__ void gload_lds16(const void* g, void* l) {
  __builtin_amdgcn_global_load_lds(
      (__attribute__((address_space(1))) void*)g,
      (__attribute__((address_space(3))) void*)l, 16, 0, 0);
}

// ---------------- fp32 -> bf16 cast (weights) ----------------
__global__ __launch_bounds__(256) void cast_w(const float* __restrict__ s,
                                              bf16* __restrict__ d, int n) {
  int i = (blockIdx.x * 256 + threadIdx.x) * 4;
  if (i >= n) return;
  float4 v = *(const float4*)(s + i);
  bf16x4 o;
  o[0] = (bf16)v.x; o[1] = (bf16)v.y; o[2] = (bf16)v.z; o[3] = (bf16)v.w;
  *(bf16x4*)(d + i) = o;
}

// ---------------- LayerNorm (fp32 in, bf16 out) ----------------
__global__ __launch_bounds__(256) void ln_kernel(const float* __restrict__ x,
                                                 const float* __restrict__ g,
                                                 const float* __restrict__ b,
                                                 bf16* __restrict__ out) {
  int row = blockIdx.x;
  int tid = threadIdx.x;
  const float* xr = x + (size_t)row * D_MODEL;
  float4 v = *(const float4*)(xr + tid * 4);
  float s  = v.x + v.y + v.z + v.w;
  float sq = v.x*v.x + v.y*v.y + v.z*v.z + v.w*v.w;
  #pragma unroll
  for (int off = 1; off < 64; off <<= 1) {
    s  += __shfl_xor(s,  off, 64);
    sq += __shfl_xor(sq, off, 64);
  }
  __shared__ float ls[4], lq[4];
  int wid = tid >> 6, lane = tid & 63;
  if (lane == 0) { ls[wid] = s; lq[wid] = sq; }
  __syncthreads();
  s  = ls[0] + ls[1] + ls[2] + ls[3];
  sq = lq[0] + lq[1] + lq[2] + lq[3];
  float mu   = s * (1.0f / D_MODEL);
  float var  = sq * (1.0f / D_MODEL) - mu * mu;
  float rstd = rsqrtf(var + 1e-5f);
  float4 gv = *(const float4*)(g + tid * 4);
  float4 bv = *(const float4*)(b + tid * 4);
  bf16x4 o;
  o[0] = (bf16)((v.x - mu) * rstd * gv.x + bv.x);
  o[1] = (bf16)((v.y - mu) * rstd * gv.y + bv.y);
  o[2] = (bf16)((v.z - mu) * rstd * gv.z + bv.z);
  o[3] = (bf16)((v.w - mu) * rstd * gv.w + bv.w);
  *(bf16x4*)(out + (size_t)row * D_MODEL + tid * 4) = o;
}

// ---------------- GEMM: C[M,N] = A[M,K] @ W[N,K]^T (+bias, epilogue) --------
enum { EP_QKV = 0, EP_RESID = 1, EP_GELU = 2 };

#define QSCALE 0.18033688011112042f  // (1/8) * log2(e)

template <int EP>
__global__ __launch_bounds__(256) void gemm_bt(
    const bf16* __restrict__ A, const bf16* __restrict__ W,
    const float* __restrict__ bias,
    const float* __restrict__ resid,
    float* __restrict__ out_f32,
    bf16* __restrict__ out_bf,
    int M, int N, int K) {
  __shared__ bf16 lA[128 * 64];
  __shared__ bf16 lB[128 * 64];
  int tiles_n = N >> 7;
  int bm = blockIdx.x / tiles_n, bn = blockIdx.x % tiles_n;
  int m0 = bm << 7, n0 = bn << 7;
  int tid = threadIdx.x, wid = tid >> 6, lane = tid & 63;
  int wm = wid >> 1, wn = wid & 1;
  int l15 = lane & 15, l4 = lane >> 4;

  f32x4 acc[4][4];
  #pragma unroll
  for (int i = 0; i < 4; i++)
    #pragma unroll
    for (int n = 0; n < 4; n++)
      #pragma unroll
      for (int e = 0; e < 4; e++) acc[i][n][e] = 0.f;

  int rA = tid >> 3;
  int c8 = (tid & 7) << 3;
  const bf16* gA = A + (size_t)(m0 + rA) * K + c8;
  const bf16* gW = W + (size_t)(n0 + rA) * K + c8;
  bf16* lAbase = lA + (wid << 9);
  bf16* lBbase = lB + (wid << 9);

  for (int kt = 0; kt < K; kt += 64) {
    __syncthreads();
    #pragma unroll
    for (int it = 0; it < 4; ++it) {
      gload_lds16(gA + (size_t)(it * 32) * K + kt, lAbase + it * 2048);
      gload_lds16(gW + (size_t)(it * 32) * K + kt, lBbase + it * 2048);
    }
    __syncthreads();
    #pragma unroll
    for (int kk = 0; kk < 2; ++kk) {
      bf16x8 af[4], bfr[4];
      #pragma unroll
      for (int i = 0; i < 4; i++) {
        af[i]  = *(const bf16x8*)(lA + (wm * 64 + i * 16 + l15) * 64 + kk * 32 + (l4 << 3));
        bfr[i] = *(const bf16x8*)(lB + (wn * 64 + i * 16 + l15) * 64 + kk * 32 + (l4 << 3));
      }
      #pragma unroll
      for (int i = 0; i < 4; i++)
        #pragma unroll
        for (int n = 0; n < 4; n++)
          acc[i][n] = __builtin_amdgcn_mfma_f32_16x16x32_bf16(af[i], bfr[n], acc[i][n], 0, 0, 0);
    }
  }

  if (EP == EP_QKV) {
    #pragma unroll
    for (int i = 0; i < 4; i++)
      #pragma unroll
      for (int n = 0; n < 4; n++) {
        int gm0 = m0 + wm * 64 + i * 16 + (l4 << 2);
        int gn  = n0 + wn * 64 + n * 16 + l15;
        int which = gn >> 10;
        int nn = gn & 1023, head = nn >> 6, d = nn & 63;
        int bb = gm0 >> 11, t = gm0 & 2047;
        float bv = bias[gn];
        if (which == 2) {
          // V transposed, fp16: vT[bh][d][t]
          f16x4 pk;
          #pragma unroll
          for (int j = 0; j < 4; j++) pk[j] = (f16)(acc[i][n][j] + bv);
          *(f16x4*)((f16*)out_bf + (size_t)2 * NBH * SEQ * DK +
                    ((size_t)(bb * NH + head) * DK + d) * SEQ + t) = pk;
        } else {
          float scale = (which == 0) ? QSCALE : 1.0f;
          #pragma unroll
          for (int j = 0; j < 4; j++) {
            float cv = (acc[i][n][j] + bv) * scale;
            size_t idx = (size_t)which * (NBH * SEQ * DK) +
                         ((size_t)(bb * NH + head) * SEQ + (t + j)) * DK + d;
            out_bf[idx] = (bf16)cv;
          }
        }
      }
  } else {
    #pragma unroll
    for (int i = 0; i < 4; i++)
      #pragma unroll
      for (int n = 0; n < 4; n++)
        #pragma unroll
        for (int j = 0; j < 4; j++) {
          int gm = m0 + wm * 64 + i * 16 + (l4 << 2) + j;
          int gn = n0 + wn * 64 + n * 16 + l15;
          float cv = acc[i][n][j] + bias[gn];
          if (EP == EP_RESID) {
            size_t idx = (size_t)gm * N + gn;
            out_f32[idx] = resid[idx] + cv;
          } else {
            float ge = 0.5f * cv * (1.0f + erff(cv * 0.70710678118654752f));
            out_bf[(size_t)gm * N + gn] = (bf16)ge;
          }
        }
  }
}

// ---------------- Flash attention (R3: register-resident P) ----------------
// grid: (T/64)*BH, 256 thr, 4 waves x 16 q-rows. KVBLK=128.
// q,k: [BH][T][DK] bf16 (q pre-scaled 0.125*log2e); vt: [BH][DK][T] fp16.
// Swapped QK^T: accs = mfma(K,Q) -> lane(l15,l4) holds S[kv=n*16+l4*4+j][q=l15].
// That register layout IS the 16x16x16f16 A-fragment -> PV directly from regs.
__global__ __launch_bounds__(256) void attn_kernel(
    const bf16* __restrict__ q, const bf16* __restrict__ k,
    const f16* __restrict__ vt, bf16* __restrict__ o) {
  __shared__ bf16 kt_lds[128 * 64];     // [kv][dk], granule16 ^= row&7
  __shared__ f16  vt_lds[64 * 128];     // [d][kv],  granule16 ^= row&15
  int bid = blockIdx.x;
  int bh = bid >> 5;
  int qt = bid & 31;
  int t0 = qt << 6;
  int tid = threadIdx.x, wid = tid >> 6, lane = tid & 63;
  int l15 = lane & 15, l4 = lane >> 4;

  // Q (B-operand): lane holds Q[q=l15][k = kk*32 + l4*8 ..+8]
  const bf16* qbase = q + ((size_t)bh * SEQ + t0 + wid * 16 + l15) * DK;
  bf16x8 qf[2];
  qf[0] = *(const bf16x8*)(qbase + (l4 << 3));
  qf[1] = *(const bf16x8*)(qbase + 32 + (l4 << 3));

  float m_run = -1e30f, l_run = 0.f;     // for q = l15 (replicated over l4)
  f32x4 acc_o[4];                        // O[q=l4*4+j][d=nd*16+l15]
  #pragma unroll
  for (int nd = 0; nd < 4; nd++)
    #pragma unroll
    for (int e = 0; e < 4; e++) acc_o[nd][e] = 0.f;

  // K staging: linear dest, source granule16 ^= row&7
  int rK = tid >> 3;
  int cK = ((tid & 7) ^ (rK & 7)) << 3;
  const bf16* gK = k + ((size_t)bh * SEQ + rK) * DK + cK;
  bf16* lK = kt_lds + (wid << 9);
  // V^T staging: rows d, 256B rows, source granule16 ^= row&15
  int rV = tid >> 4;
  int cV = ((tid & 15) ^ rV) << 3;
  const f16* gV = vt + ((size_t)bh * DK + rV) * SEQ + cV;
  f16* lV = vt_lds + (wid << 9);

  for (int kv0 = 0; kv0 < SEQ; kv0 += 128) {
    __syncthreads();
    #pragma unroll
    for (int it = 0; it < 4; ++it) {
      gload_lds16(gK + (size_t)(kv0 + it * 32) * DK, lK + it * 2048);
      gload_lds16(gV + (size_t)(it * 16) * SEQ + kv0, lV + it * 2048);
    }
    __syncthreads();

    // S = K Q^T (swapped): accs[n][j] = S[kv = n*16+l4*4+j][q=l15]
    f32x4 accs[8];
    #pragma unroll
    for (int n = 0; n < 8; n++) {
      #pragma unroll
      for (int e = 0; e < 4; e++) accs[n][e] = 0.f;
      #pragma unroll
      for (int kk = 0; kk < 2; kk++) {
        int rowk = n * 16 + l15;
        bf16x8 kf = *(const bf16x8*)(kt_lds + rowk * 64 + ((((kk << 2) + l4) ^ (rowk & 7)) << 3));
        accs[n] = __builtin_amdgcn_mfma_f32_16x16x32_bf16(kf, qf[kk], accs[n], 0, 0, 0);
      }
    }

    // online softmax (log2 domain), lane-local row q=l15
    float mloc = -1e30f;
    #pragma unroll
    for (int n = 0; n < 8; n++)
      #pragma unroll
      for (int j = 0; j < 4; j++) mloc = fmaxf(mloc, accs[n][j]);
    float mt = fmaxf(mloc, __shfl_xor(mloc, 16, 64));
    mt = fmaxf(mt, __shfl_xor(mt, 32, 64));
    if (__any(mt > m_run + 8.0f)) {
      float mn = fmaxf(m_run, mt);
      float sc = exp2f(m_run - mn);
      m_run = mn;
      l_run *= sc;
      float scr0 = __shfl(sc, l4 * 20 + 0, 64);
      float scr1 = __shfl(sc, l4 * 20 + 1, 64);
      float scr2 = __shfl(sc, l4 * 20 + 2, 64);
      float scr3 = __shfl(sc, l4 * 20 + 3, 64);
      #pragma unroll
      for (int nd = 0; nd < 4; nd++) {
        acc_o[nd][0] *= scr0; acc_o[nd][1] *= scr1;
        acc_o[nd][2] *= scr2; acc_o[nd][3] *= scr3;
      }
    }
    // P = exp2(S - m_run): directly into 16x16x16 f16 A-fragments
    f16x4 pa[8];
    float ls = 0.f;
    #pragma unroll
    for (int n = 0; n < 8; n++)
      #pragma unroll
      for (int j = 0; j < 4; j++) {
        float pv = exp2f(accs[n][j] - m_run);
        ls += pv;
        pa[n][j] = (f16)pv;
      }
    ls += __shfl_xor(ls, 16, 64);
    ls += __shfl_xor(ls, 32, 64);
    l_run += ls;

    // O += P @ V : A = pa[kk] (regs), B = V^T rows d (f16, b64 reads)
    #pragma unroll
    for (int kk = 0; kk < 8; kk++) {
      #pragma unroll
      for (int nd = 0; nd < 4; nd++) {
        int rowv = nd * 16 + l15;
        int g = (kk << 1) + (l4 >> 1);
        f16x4 vf = *(const f16x4*)((const char*)vt_lds + rowv * 256 +
                                   (((g ^ (rowv & 15)) << 4) + ((l4 & 1) << 3)));
        acc_o[nd] = __builtin_amdgcn_mfma_f32_16x16x16f16(pa[kk], vf, acc_o[nd], 0, 0, 0);
      }
    }
  }

  float lr0 = __shfl(l_run, l4 * 20 + 0, 64);
  float lr1 = __shfl(l_run, l4 * 20 + 1, 64);
  float lr2 = __shfl(l_run, l4 * 20 + 2, 64);
  float lr3 = __shfl(l_run, l4 * 20 + 3, 64);
  int bb = bh >> 4, hh = bh & 15;
  #pragma unroll
  for (int nd = 0; nd < 4; nd++) {
    int d = nd * 16 + l15;
    int rowb = t0 + wid * 16 + l4 * 4;
    o[((size_t)bb * SEQ + rowb + 0) * D_MODEL + hh * DK + d] = (bf16)(acc_o[nd][0] / lr0);
    o[((size_t)bb * SEQ + rowb + 1) * D_MODEL + hh * DK + d] = (bf16)(acc_o[nd][1] / lr1);
    o[((size_t)bb * SEQ + rowb + 2) * D_MODEL + hh * DK + d] = (bf16)(acc_o[nd][2] / lr2);
    o[((size_t)bb * SEQ + rowb + 3) * D_MODEL + hh * DK + d] = (bf16)(acc_o[nd][3] / lr3);
  }
}

// ---------------- launch ----------------
extern "C" void kernel_launch(void* const* d_in, const int* in_sizes, int n_in,
                              void* d_out, int out_size, void* d_ws, size_t ws_size,
                              hipStream_t stream) {
  const float* x    = (const float*)d_in[0];
  const float* ln1g = (const float*)d_in[1];
  const float* ln1b = (const float*)d_in[2];
  const float* wq   = (const float*)d_in[3];
  const float* bq   = (const float*)d_in[4];
  const float* wk   = (const float*)d_in[5];
  const float* bk   = (const float*)d_in[6];
  const float* wv   = (const float*)d_in[7];
  const float* bv   = (const float*)d_in[8];
  const float* wo   = (const float*)d_in[9];
  const float* bo   = (const float*)d_in[10];
  const float* ln2g = (const float*)d_in[11];
  const float* ln2b = (const float*)d_in[12];
  const float* w1   = (const float*)d_in[13];
  const float* b1   = (const float*)d_in[14];
  const float* w2   = (const float*)d_in[15];
  const float* b2   = (const float*)d_in[16];
  float* out = (float*)d_out;

  char* ws = (char*)d_ws;
  bf16* wqkv_b = (bf16*)(ws);                          // 6MB
  bf16* wo_b   = (bf16*)(ws + ((size_t)6  << 20));     // 2MB
  bf16* w1_b   = (bf16*)(ws + ((size_t)8  << 20));     // 8MB
  bf16* w2_b   = (bf16*)(ws + ((size_t)16 << 20));     // 8MB
  bf16* h_b    = (bf16*)(ws + ((size_t)24 << 20));     // 16MB
  bf16* qkv_b  = (bf16*)(ws + ((size_t)40 << 20));     // 48MB q|k|vT(f16)
  bf16* o_b    = (bf16*)(ws + ((size_t)88 << 20));     // 16MB
  bf16* ffn1_b = (bf16*)(ws + ((size_t)40 << 20));     // 64MB (over dead q,k,v,o)
  float* bqkv  = (float*)(ws + ((size_t)104 << 20));   // 12KB

  cast_w<<<1024, 256, 0, stream>>>(wq, wqkv_b, 1 << 20);
  cast_w<<<1024, 256, 0, stream>>>(wk, wqkv_b + (1 << 20), 1 << 20);
  cast_w<<<1024, 256, 0, stream>>>(wv, wqkv_b + (2 << 20), 1 << 20);
  cast_w<<<1024, 256, 0, stream>>>(wo, wo_b, 1 << 20);
  cast_w<<<4096, 256, 0, stream>>>(w1, w1_b, 1 << 22);
  cast_w<<<4096, 256, 0, stream>>>(w2, w2_b, 1 << 22);
  hipMemcpyAsync(bqkv,        bq, 4096, hipMemcpyDeviceToDevice, stream);
  hipMemcpyAsync(bqkv + 1024, bk, 4096, hipMemcpyDeviceToDevice, stream);
  hipMemcpyAsync(bqkv + 2048, bv, 4096, hipMemcpyDeviceToDevice, stream);

  ln_kernel<<<MTOK, 256, 0, stream>>>(x, ln1g, ln1b, h_b);
  gemm_bt<EP_QKV><<<64 * 24, 256, 0, stream>>>(h_b, wqkv_b, bqkv, nullptr, nullptr,
                                               qkv_b, MTOK, 3072, 1024);
  attn_kernel<<<NBH * 32, 256, 0, stream>>>(qkv_b, qkv_b + (size_t)NBH * SEQ * DK,
                                            (const f16*)(qkv_b + (size_t)2 * NBH * SEQ * DK),
                                            o_b);
  gemm_bt<EP_RESID><<<64 * 8, 256, 0, stream>>>(o_b, wo_b, bo, x, out, nullptr,
                                                MTOK, 1024, 1024);
  ln_kernel<<<MTOK, 256, 0, stream>>>(out, ln2g, ln2b, h_b);
  gemm_bt<EP_GELU><<<64 * 32, 256, 0, stream>>>(h_b, w1_b, b1, nullptr, nullptr,
                                                ffn1_b, MTOK, 4096, 1024);
  gemm_bt<EP_RESID><<<64 * 8, 256, 0, stream>>>(ffn1_b, w2_b, b2, out, out, nullptr,
                                                MTOK, 1024, 4096);
}

// Round 5
// 502.106 us; speedup vs baseline: 1.3913x; 1.0451x over previous
//
#include <hip/hip_runtime.h>
#include <math.h>

// EncoderBlock: pre-LN attention + FFN, bf16 MFMA compute, fp32 residual spine.
// B=4 T=2048 D=1024 H=16 dk=64 DFF=4096
// R1: XOR-swizzle attn LDS tiles; q pre-scaled.
// R2: V^T staged via global_load_lds; KVBLK=128; exp2 softmax; defer-max.
// R3: swapped QK^T -> lane-local P; PV via 16x16x16f16 from P registers.
// R4: all GEMMs -> 256x128-tile 8-wave deep-pipelined kernel (T2 swizzle +
//     T3/T4 counted vmcnt(3) phases + T5 setprio + T1 XCD swizzle).

#define D_MODEL 1024
#define D_FF    4096
#define NH      16
#define BATCH   4
#define SEQ     2048
#define DK      64
#define MTOK    (BATCH*SEQ)   // 8192
#define NBH     (BATCH*NH)    // 64

typedef __bf16 bf16;
typedef _Float16 f16;
typedef bf16  bf16x4 __attribute__((ext_vector_type(4)));
typedef bf16  bf16x8 __attribute__((ext_vector_type(8)));
typedef f16   f16x4  __attribute__((ext_vector_type(4)));
typedef float f32x4  __attribute__((ext_vector_type(4)));

__device__ __forceinline__ void gload_lds16(const void* g, void* l) {
  __builtin_amdgcn_global_load_lds(
      (__attribute__((address_space(1))) void*)g,
      (__attribute__((address_space(3))) void*)l, 16, 0, 0);
}

#define BAR() __builtin_amdgcn_s_barrier()
#define WAIT_VM3() do { asm volatile("s_waitcnt vmcnt(3)" ::: "memory"); \
  __builtin_amdgcn_sched_barrier(0); } while (0)
#define WAIT_VM0() do { asm volatile("s_waitcnt vmcnt(0)" ::: "memory"); \
  __builtin_amdgcn_sched_barrier(0); } while (0)
#define WAIT_LGKM0() do { asm volatile("s_waitcnt lgkmcnt(0)" ::: "memory"); } while (0)

// ---------------- fp32 -> bf16 cast (weights) ----------------
__global__ __launch_bounds__(256) void cast_w(const float* __restrict__ s,
                                              bf16* __restrict__ d, int n) {
  int i = (blockIdx.x * 256 + threadIdx.x) * 4;
  if (i >= n) return;
  float4 v = *(const float4*)(s + i);
  bf16x4 o;
  o[0] = (bf16)v.x; o[1] = (bf16)v.y; o[2] = (bf16)v.z; o[3] = (bf16)v.w;
  *(bf16x4*)(d + i) = o;
}

// ---------------- LayerNorm (fp32 in, bf16 out) ----------------
__global__ __launch_bounds__(256) void ln_kernel(const float* __restrict__ x,
                                                 const float* __restrict__ g,
                                                 const float* __restrict__ b,
                                                 bf16* __restrict__ out) {
  int row = blockIdx.x;
  int tid = threadIdx.x;
  const float* xr = x + (size_t)row * D_MODEL;
  float4 v = *(const float4*)(xr + tid * 4);
  float s  = v.x + v.y + v.z + v.w;
  float sq = v.x*v.x + v.y*v.y + v.z*v.z + v.w*v.w;
  #pragma unroll
  for (int off = 1; off < 64; off <<= 1) {
    s  += __shfl_xor(s,  off, 64);
    sq += __shfl_xor(sq, off, 64);
  }
  __shared__ float ls[4], lq[4];
  int wid = tid >> 6, lane = tid & 63;
  if (lane == 0) { ls[wid] = s; lq[wid] = sq; }
  __syncthreads();
  s  = ls[0] + ls[1] + ls[2] + ls[3];
  sq = lq[0] + lq[1] + lq[2] + lq[3];
  float mu   = s * (1.0f / D_MODEL);
  float var  = sq * (1.0f / D_MODEL) - mu * mu;
  float rstd = rsqrtf(var + 1e-5f);
  float4 gv = *(const float4*)(g + tid * 4);
  float4 bv = *(const float4*)(b + tid * 4);
  bf16x4 o;
  o[0] = (bf16)((v.x - mu) * rstd * gv.x + bv.x);
  o[1] = (bf16)((v.y - mu) * rstd * gv.y + bv.y);
  o[2] = (bf16)((v.z - mu) * rstd * gv.z + bv.z);
  o[3] = (bf16)((v.w - mu) * rstd * gv.w + bv.w);
  *(bf16x4*)(out + (size_t)row * D_MODEL + tid * 4) = o;
}

// ---------------- GEMM: C[M,N] = A[M,K] @ W[N,K]^T (+bias, epilogue) --------
// 256x128 tile, BK=64, 8 waves (4m x 2n, wave-tile 64x64), deep pipeline:
// per K-tile 2 phases (k-halves); each phase: 8 ds_read_b128 + 3 gload_lds of
// tile t+1 -> barrier -> lgkmcnt(0) -> setprio(1) 16 MFMA setprio(0) ->
// vmcnt(3) -> barrier.  LDS double-buffered 2x(32K A + 16K B) = 96KB, granule
// swizzle g^=row&3 on both stage-source and ds_read.
enum { EP_QKV = 0, EP_RESID = 1, EP_GELU = 2 };

#define QSCALE 0.18033688011112042f  // (1/8) * log2(e)

template <int EP>
__global__ __launch_bounds__(512) void gemm256(
    const bf16* __restrict__ A, const bf16* __restrict__ W,
    const float* __restrict__ bias,
    const float* __restrict__ resid,
    float* __restrict__ out_f32,
    bf16* __restrict__ out_bf,
    int M, int N, int K) {
  __shared__ char lds[98304];   // buf c: A @ c*49152 (2 kh x 256 x 32), B @ +32768 (2 kh x 128 x 32)
  int tiles_n = N >> 7;
  int nwg = (M >> 8) * tiles_n;
  int bid = blockIdx.x;
  int swz = (bid & 7) * (nwg >> 3) + (bid >> 3);   // XCD-contiguous chunks
  int bm = swz / tiles_n, bn = swz % tiles_n;
  int m0 = bm << 8, n0 = bn << 7;
  int tid = threadIdx.x, wid = tid >> 6, lane = tid & 63;
  int wm = wid >> 1, wn = wid & 1;
  int l15 = lane & 15, l4 = lane >> 4;
  int gsw = (l4 ^ (l15 & 3)) << 4;                 // read-side granule swizzle (bytes)
  int csw = ((tid & 3) ^ ((tid >> 2) & 3)) << 3;   // stage-side source col swizzle (elems)
  int rT  = tid >> 2;                              // staging row within half

  f32x4 acc[4][4];
  #pragma unroll
  for (int i = 0; i < 4; i++)
    #pragma unroll
    for (int j = 0; j < 4; j++)
      #pragma unroll
      for (int e = 0; e < 4; e++) acc[i][j][e] = 0.f;

  const size_t rowAa = (size_t)(m0 + rT) * K;
  const size_t rowAb = (size_t)(m0 + 128 + rT) * K;
  const size_t rowB  = (size_t)(n0 + rT) * K;
  char* ldsp = lds;

  // STAGE one k-half (kh) of K-tile kt into buffer nb: 3 gload_lds/thread.
  auto STAGE = [&](int kh, int kt, int nb) {
    size_t koff = (size_t)kt * 64 + kh * 32 + csw;
    char* dA = ldsp + nb * 49152 + kh * 16384 + (wid << 10);
    char* dB = ldsp + nb * 49152 + 32768 + kh * 8192 + (wid << 10);
    gload_lds16(A + rowAa + koff, dA);
    gload_lds16(A + rowAb + koff, dA + 8192);
    gload_lds16(W + rowB + koff, dB);
  };

  int nt = K >> 6;
  STAGE(0, 0, 0); STAGE(1, 0, 0);
  WAIT_VM3(); BAR();

  for (int t = 0; t < nt - 1; ++t) {
    int cb = t & 1, nb = cb ^ 1;
    #pragma unroll
    for (int kh = 0; kh < 2; ++kh) {
      bf16x8 af[4], bq[4];
      const char* pa = ldsp + cb * 49152 + kh * 16384 + gsw;
      const char* pb = ldsp + cb * 49152 + 32768 + kh * 8192 + gsw;
      #pragma unroll
      for (int i = 0; i < 4; i++)
        af[i] = *(const bf16x8*)(pa + (wm * 64 + i * 16 + l15) * 64);
      #pragma unroll
      for (int j = 0; j < 4; j++)
        bq[j] = *(const bf16x8*)(pb + (wn * 64 + j * 16 + l15) * 64);
      STAGE(kh, t + 1, nb);
      BAR();
      WAIT_LGKM0();
      __builtin_amdgcn_s_setprio(1);
      #pragma unroll
      for (int i = 0; i < 4; i++)
        #pragma unroll
        for (int j = 0; j < 4; j++)
          acc[i][j] = __builtin_amdgcn_mfma_f32_16x16x32_bf16(af[i], bq[j], acc[i][j], 0, 0, 0);
      __builtin_amdgcn_s_setprio(0);
      WAIT_VM3(); BAR();
    }
  }
  // peeled last K-tile (no staging; drain)
  {
    int cb = (nt - 1) & 1;
    #pragma unroll
    for (int kh = 0; kh < 2; ++kh) {
      bf16x8 af[4], bq[4];
      const char* pa = ldsp + cb * 49152 + kh * 16384 + gsw;
      const char* pb = ldsp + cb * 49152 + 32768 + kh * 8192 + gsw;
      #pragma unroll
      for (int i = 0; i < 4; i++)
        af[i] = *(const bf16x8*)(pa + (wm * 64 + i * 16 + l15) * 64);
      #pragma unroll
      for (int j = 0; j < 4; j++)
        bq[j] = *(const bf16x8*)(pb + (wn * 64 + j * 16 + l15) * 64);
      WAIT_LGKM0();
      #pragma unroll
      for (int i = 0; i < 4; i++)
        #pragma unroll
        for (int j = 0; j < 4; j++)
          acc[i][j] = __builtin_amdgcn_mfma_f32_16x16x32_bf16(af[i], bq[j], acc[i][j], 0, 0, 0);
      if (kh == 0) { WAIT_VM0(); BAR(); }
    }
  }

  // ----- epilogue -----
  if (EP == EP_QKV) {
    #pragma unroll
    for (int i = 0; i < 4; i++)
      #pragma unroll
      for (int j = 0; j < 4; j++) {
        int gm0 = m0 + wm * 64 + i * 16 + (l4 << 2);
        int gn  = n0 + wn * 64 + j * 16 + l15;
        int which = gn >> 10;
        int nn = gn & 1023, head = nn >> 6, d = nn & 63;
        int bb = gm0 >> 11, t = gm0 & 2047;
        float bv = bias[gn];
        if (which == 2) {
          f16x4 pk;
          #pragma unroll
          for (int jj = 0; jj < 4; jj++) pk[jj] = (f16)(acc[i][j][jj] + bv);
          *(f16x4*)((f16*)out_bf + (size_t)2 * NBH * SEQ * DK +
                    ((size_t)(bb * NH + head) * DK + d) * SEQ + t) = pk;
        } else {
          float scale = (which == 0) ? QSCALE : 1.0f;
          #pragma unroll
          for (int jj = 0; jj < 4; jj++) {
            float cv = (acc[i][j][jj] + bv) * scale;
            size_t idx = (size_t)which * (NBH * SEQ * DK) +
                         ((size_t)(bb * NH + head) * SEQ + (t + jj)) * DK + d;
            out_bf[idx] = (bf16)cv;
          }
        }
      }
  } else {
    #pragma unroll
    for (int i = 0; i < 4; i++)
      #pragma unroll
      for (int j = 0; j < 4; j++)
        #pragma unroll
        for (int jj = 0; jj < 4; jj++) {
          int gm = m0 + wm * 64 + i * 16 + (l4 << 2) + jj;
          int gn = n0 + wn * 64 + j * 16 + l15;
          float cv = acc[i][j][jj] + bias[gn];
          if (EP == EP_RESID) {
            size_t idx = (size_t)gm * N + gn;
            out_f32[idx] = resid[idx] + cv;
          } else {
            float ge = 0.5f * cv * (1.0f + erff(cv * 0.70710678118654752f));
            out_bf[(size_t)gm * N + gn] = (bf16)ge;
          }
        }
  }
}

// ---------------- Flash attention (register-resident P) ----------------
__global__ __launch_bounds__(256) void attn_kernel(
    const bf16* __restrict__ q, const bf16* __restrict__ k,
    const f16* __restrict__ vt, bf16* __restrict__ o) {
  __shared__ bf16 kt_lds[128 * 64];     // [kv][dk], granule16 ^= row&7
  __shared__ f16  vt_lds[64 * 128];     // [d][kv],  granule16 ^= row&15
  int bid = blockIdx.x;
  int bh = bid >> 5;
  int qt = bid & 31;
  int t0 = qt << 6;
  int tid = threadIdx.x, wid = tid >> 6, lane = tid & 63;
  int l15 = lane & 15, l4 = lane >> 4;

  const bf16* qbase = q + ((size_t)bh * SEQ + t0 + wid * 16 + l15) * DK;
  bf16x8 qf[2];
  qf[0] = *(const bf16x8*)(qbase + (l4 << 3));
  qf[1] = *(const bf16x8*)(qbase + 32 + (l4 << 3));

  float m_run = -1e30f, l_run = 0.f;
  f32x4 acc_o[4];
  #pragma unroll
  for (int nd = 0; nd < 4; nd++)
    #pragma unroll
    for (int e = 0; e < 4; e++) acc_o[nd][e] = 0.f;

  int rK = tid >> 3;
  int cK = ((tid & 7) ^ (rK & 7)) << 3;
  const bf16* gK = k + ((size_t)bh * SEQ + rK) * DK + cK;
  bf16* lK = kt_lds + (wid << 9);
  int rV = tid >> 4;
  int cV = ((tid & 15) ^ rV) << 3;
  const f16* gV = vt + ((size_t)bh * DK + rV) * SEQ + cV;
  f16* lV = vt_lds + (wid << 9);

  for (int kv0 = 0; kv0 < SEQ; kv0 += 128) {
    __syncthreads();
    #pragma unroll
    for (int it = 0; it < 4; ++it) {
      gload_lds16(gK + (size_t)(kv0 + it * 32) * DK, lK + it * 2048);
      gload_lds16(gV + (size_t)(it * 16) * SEQ + kv0, lV + it * 2048);
    }
    __syncthreads();

    f32x4 accs[8];
    #pragma unroll
    for (int n = 0; n < 8; n++) {
      #pragma unroll
      for (int e = 0; e < 4; e++) accs[n][e] = 0.f;
      #pragma unroll
      for (int kk = 0; kk < 2; kk++) {
        int rowk = n * 16 + l15;
        bf16x8 kf = *(const bf16x8*)(kt_lds + rowk * 64 + ((((kk << 2) + l4) ^ (rowk & 7)) << 3));
        accs[n] = __builtin_amdgcn_mfma_f32_16x16x32_bf16(kf, qf[kk], accs[n], 0, 0, 0);
      }
    }

    float mloc = -1e30f;
    #pragma unroll
    for (int n = 0; n < 8; n++)
      #pragma unroll
      for (int j = 0; j < 4; j++) mloc = fmaxf(mloc, accs[n][j]);
    float mt = fmaxf(mloc, __shfl_xor(mloc, 16, 64));
    mt = fmaxf(mt, __shfl_xor(mt, 32, 64));
    if (__any(mt > m_run + 8.0f)) {
      float mn = fmaxf(m_run, mt);
      float sc = exp2f(m_run - mn);
      m_run = mn;
      l_run *= sc;
      float scr0 = __shfl(sc, l4 * 20 + 0, 64);
      float scr1 = __shfl(sc, l4 * 20 + 1, 64);
      float scr2 = __shfl(sc, l4 * 20 + 2, 64);
      float scr3 = __shfl(sc, l4 * 20 + 3, 64);
      #pragma unroll
      for (int nd = 0; nd < 4; nd++) {
        acc_o[nd][0] *= scr0; acc_o[nd][1] *= scr1;
        acc_o[nd][2] *= scr2; acc_o[nd][3] *= scr3;
      }
    }
    f16x4 pa[8];
    float ls = 0.f;
    #pragma unroll
    for (int n = 0; n < 8; n++)
      #pragma unroll
      for (int j = 0; j < 4; j++) {
        float pv = exp2f(accs[n][j] - m_run);
        ls += pv;
        pa[n][j] = (f16)pv;
      }
    ls += __shfl_xor(ls, 16, 64);
    ls += __shfl_xor(ls, 32, 64);
    l_run += ls;

    #pragma unroll
    for (int kk = 0; kk < 8; kk++) {
      #pragma unroll
      for (int nd = 0; nd < 4; nd++) {
        int rowv = nd * 16 + l15;
        int g = (kk << 1) + (l4 >> 1);
        f16x4 vf = *(const f16x4*)((const char*)vt_lds + rowv * 256 +
                                   (((g ^ (rowv & 15)) << 4) + ((l4 & 1) << 3)));
        acc_o[nd] = __builtin_amdgcn_mfma_f32_16x16x16f16(pa[kk], vf, acc_o[nd], 0, 0, 0);
      }
    }
  }

  float lr0 = __shfl(l_run, l4 * 20 + 0, 64);
  float lr1 = __shfl(l_run, l4 * 20 + 1, 64);
  float lr2 = __shfl(l_run, l4 * 20 + 2, 64);
  float lr3 = __shfl(l_run, l4 * 20 + 3, 64);
  int bb = bh >> 4, hh = bh & 15;
  #pragma unroll
  for (int nd = 0; nd < 4; nd++) {
    int d = nd * 16 + l15;
    int rowb = t0 + wid * 16 + l4 * 4;
    o[((size_t)bb * SEQ + rowb + 0) * D_MODEL + hh * DK + d] = (bf16)(acc_o[nd][0] / lr0);
    o[((size_t)bb * SEQ + rowb + 1) * D_MODEL + hh * DK + d] = (bf16)(acc_o[nd][1] / lr1);
    o[((size_t)bb * SEQ + rowb + 2) * D_MODEL + hh * DK + d] = (bf16)(acc_o[nd][2] / lr2);
    o[((size_t)bb * SEQ + rowb + 3) * D_MODEL + hh * DK + d] = (bf16)(acc_o[nd][3] / lr3);
  }
}

// ---------------- launch ----------------
extern "C" void kernel_launch(void* const* d_in, const int* in_sizes, int n_in,
                              void* d_out, int out_size, void* d_ws, size_t ws_size,
                              hipStream_t stream) {
  const float* x    = (const float*)d_in[0];
  const float* ln1g = (const float*)d_in[1];
  const float* ln1b = (const float*)d_in[2];
  const float* wq   = (const float*)d_in[3];
  const float* bq   = (const float*)d_in[4];
  const float* wk   = (const float*)d_in[5];
  const float* bk   = (const float*)d_in[6];
  const float* wv   = (const float*)d_in[7];
  const float* bv   = (const float*)d_in[8];
  const float* wo   = (const float*)d_in[9];
  const float* bo   = (const float*)d_in[10];
  const float* ln2g = (const float*)d_in[11];
  const float* ln2b = (const float*)d_in[12];
  const float* w1   = (const float*)d_in[13];
  const float* b1   = (const float*)d_in[14];
  const float* w2   = (const float*)d_in[15];
  const float* b2   = (const float*)d_in[16];
  float* out = (float*)d_out;

  char* ws = (char*)d_ws;
  bf16* wqkv_b = (bf16*)(ws);                          // 6MB
  bf16* wo_b   = (bf16*)(ws + ((size_t)6  << 20));     // 2MB
  bf16* w1_b   = (bf16*)(ws + ((size_t)8  << 20));     // 8MB
  bf16* w2_b   = (bf16*)(ws + ((size_t)16 << 20));     // 8MB
  bf16* h_b    = (bf16*)(ws + ((size_t)24 << 20));     // 16MB
  bf16* qkv_b  = (bf16*)(ws + ((size_t)40 << 20));     // 48MB q|k|vT(f16)
  bf16* o_b    = (bf16*)(ws + ((size_t)88 << 20));     // 16MB
  bf16* ffn1_b = (bf16*)(ws + ((size_t)40 << 20));     // 64MB (over dead q,k,v,o)
  float* bqkv  = (float*)(ws + ((size_t)104 << 20));   // 12KB

  cast_w<<<1024, 256, 0, stream>>>(wq, wqkv_b, 1 << 20);
  cast_w<<<1024, 256, 0, stream>>>(wk, wqkv_b + (1 << 20), 1 << 20);
  cast_w<<<1024, 256, 0, stream>>>(wv, wqkv_b + (2 << 20), 1 << 20);
  cast_w<<<1024, 256, 0, stream>>>(wo, wo_b, 1 << 20);
  cast_w<<<4096, 256, 0, stream>>>(w1, w1_b, 1 << 22);
  cast_w<<<4096, 256, 0, stream>>>(w2, w2_b, 1 << 22);
  hipMemcpyAsync(bqkv,        bq, 4096, hipMemcpyDeviceToDevice, stream);
  hipMemcpyAsync(bqkv + 1024, bk, 4096, hipMemcpyDeviceToDevice, stream);
  hipMemcpyAsync(bqkv + 2048, bv, 4096, hipMemcpyDeviceToDevice, stream);

  ln_kernel<<<MTOK, 256, 0, stream>>>(x, ln1g, ln1b, h_b);
  gemm256<EP_QKV><<<768, 512, 0, stream>>>(h_b, wqkv_b, bqkv, nullptr, nullptr,
                                           qkv_b, MTOK, 3072, 1024);
  attn_kernel<<<NBH * 32, 256, 0, stream>>>(qkv_b, qkv_b + (size_t)NBH * SEQ * DK,
                                            (const f16*)(qkv_b + (size_t)2 * NBH * SEQ * DK),
                                            o_b);
  gemm256<EP_RESID><<<256, 512, 0, stream>>>(o_b, wo_b, bo, x, out, nullptr,
                                             MTOK, 1024, 1024);
  ln_kernel<<<MTOK, 256, 0, stream>>>(out, ln2g, ln2b, h_b);
  gemm256<EP_GELU><<<1024, 512, 0, stream>>>(h_b, w1_b, b1, nullptr, nullptr,
                                             ffn1_b, MTOK, 4096, 1024);
  gemm256<EP_RESID><<<256, 512, 0, stream>>>(ffn1_b, w2_b, b2, out, out, nullptr,
                                             MTOK, 1024, 4096);
}